// Round 1
// baseline (362.917 us; speedup 1.0000x reference)
//
#include <hip/hip_runtime.h>

// Round 0: correctness-first dense build.
//   Kernel 1: zero-fill D*D f32 output with float4 stores, writing h_local on diag.
//   Kernel 2: scatter V_interaction * scale to (i,j) and (j,i). Indices unique -> no atomics.

__global__ __launch_bounds__(256) void fill_diag_kernel(
    float* __restrict__ out,
    const float* __restrict__ h_local,
    int logd,            // log2(D)
    long long n4)        // D*D/4 float4 chunks
{
    long long t = (long long)blockIdx.x * blockDim.x + threadIdx.x;
    if (t >= n4) return;
    long long b = t << 2;                 // element index of chunk start
    int d_mask = (1 << logd) - 1;
    int row  = (int)(b >> logd);
    int col0 = (int)(b & d_mask);

    float vals[4] = {0.f, 0.f, 0.f, 0.f};
    int dcol = row - col0;                // position of diagonal element in this chunk
    if (dcol >= 0 && dcol < 4) {
        vals[dcol] = h_local[row];
    }
    float4 v = make_float4(vals[0], vals[1], vals[2], vals[3]);
    reinterpret_cast<float4*>(out)[t] = v;
}

__global__ __launch_bounds__(256) void scatter_kernel(
    float* __restrict__ out,
    const int* __restrict__ idx,          // [2, M] int32: row 0 = i, row 1 = j
    const float* __restrict__ vals,       // [M]
    float scale,
    int m,
    int logd)
{
    int k = blockIdx.x * blockDim.x + threadIdx.x;
    if (k >= m) return;
    int i = idx[k];
    int j = idx[m + k];
    float v = vals[k] * scale;
    out[((long long)i << logd) + j] = v;
    out[((long long)j << logd) + i] = v;
}

extern "C" void kernel_launch(void* const* d_in, const int* in_sizes, int n_in,
                              void* d_out, int out_size, void* d_ws, size_t ws_size,
                              hipStream_t stream) {
    const float* h_local = (const float*)d_in[0];
    const float* V_int   = (const float*)d_in[1];
    const int*   idx     = (const int*)d_in[2];
    // d_in[3] = dimension scalar; D also equals in_sizes[0].

    const int d = in_sizes[0];            // 8192
    const int m = in_sizes[1];            // 1,600,000

    // log2(d); d is a power of two (8192).
    int logd = 0;
    while ((1 << logd) < d) ++logd;

    const double iscale_d = 1.0 - 0.2 / sqrt(log((double)d));
    const float  iscale   = (float)iscale_d;

    float* out = (float*)d_out;

    // Kernel 1: zero + diagonal. D*D/4 float4 chunks.
    const long long n4 = ((long long)d * d) >> 2;
    const int block = 256;
    const long long grid_fill = (n4 + block - 1) / block;
    fill_diag_kernel<<<(dim3)(unsigned)grid_fill, block, 0, stream>>>(out, h_local, logd, n4);

    // Kernel 2: symmetric scatter (stream-ordered after the fill).
    const int grid_sc = (m + block - 1) / block;
    scatter_kernel<<<grid_sc, block, 0, stream>>>(out, idx, V_int, iscale, m, logd);
}